// Round 14
// baseline (183.591 us; speedup 1.0000x reference)
//
#include <hip/hip_runtime.h>
#include <hip/hip_bf16.h>
#include <stdint.h>

// Attention: b=4, n=4097, d=128, h=8, dh=16, scale = d**-0.5.
// Interface (R5): fp32 in, fp32 out, ws >= 33.6MB usable.
// R27: DIAGNOSTIC. Ledger proves the ~87us non-attn residual is INVARIANT
// to out_mfma implementation (R21's lightest-possible out: residual 86.6)
// and to qkv wave count (R26) -> prime suspect is qkv itself (frozen since
// R18, never directly measured; first-principles model says 6-8us -> 10x
// discrepancy = blind spot). The top-5 table is always masked by 88us attn
// rows, so: R25 config byte-frozen + attn split into TWO qt-halves
// ((9,32,4) + (8,32,4) blocks, body unchanged, qt_off scalar arg). Halves
// ~46-56us each => any kernel >=~55us MUST surface in top-5.
// Readout: qkv>50 -> attack qkv next; out>50 -> attack out; nothing -> both
// <50, residual is overhead, revert to R25 and declare plateau.

#define BB 4
#define NN 4097
#define NNP 4112
#define DD 128
#define HH 8
#define DH 16
#define BH (BB*HH)    // 32
#define ROWS (BB*NN)  // 16388
#define MT  1025      // ceil(ROWS/16) m-tiles
#define NSP 4         // attention key-splits (R13-proven)

typedef _Float16 h4 __attribute__((ext_vector_type(4)));
typedef _Float16 h8 __attribute__((ext_vector_type(8)));
typedef __fp16   fp16v2 __attribute__((ext_vector_type(2)));
typedef float    f4 __attribute__((ext_vector_type(4)));

#define QSCALE (0.08838834764831845f * 1.4426950408889634f)  // 128^-.5 * log2e

#if __has_builtin(__builtin_amdgcn_exp2f)
#define EXP2F(x) __builtin_amdgcn_exp2f(x)
#else
#define EXP2F(x) exp2f(x)
#endif

union H4u { h4 v; fp16v2 p[2]; };
union H8u { h8 v; fp16v2 p[4]; };

static __device__ __forceinline__ H4u pack4u(float a, float b, float c, float d) {
    H4u u;
#if __has_builtin(__builtin_amdgcn_cvt_pkrtz)
    u.p[0] = __builtin_amdgcn_cvt_pkrtz(a, b);
    u.p[1] = __builtin_amdgcn_cvt_pkrtz(c, d);
#else
    u.v[0] = (_Float16)a; u.v[1] = (_Float16)b; u.v[2] = (_Float16)c; u.v[3] = (_Float16)d;
#endif
    return u;
}

static __device__ __forceinline__ h8 pack8u(const float4& t0, const float4& t1) {
    H8u u;
#if __has_builtin(__builtin_amdgcn_cvt_pkrtz)
    u.p[0] = __builtin_amdgcn_cvt_pkrtz(t0.x, t0.y);
    u.p[1] = __builtin_amdgcn_cvt_pkrtz(t0.z, t0.w);
    u.p[2] = __builtin_amdgcn_cvt_pkrtz(t1.x, t1.y);
    u.p[3] = __builtin_amdgcn_cvt_pkrtz(t1.z, t1.w);
#else
    u.v[0]=(_Float16)t0.x; u.v[1]=(_Float16)t0.y; u.v[2]=(_Float16)t0.z; u.v[3]=(_Float16)t0.w;
    u.v[4]=(_Float16)t1.x; u.v[5]=(_Float16)t1.y; u.v[6]=(_Float16)t1.z; u.v[7]=(_Float16)t1.w;
#endif
    return u.v;
}

// ---------------- K0: prep — W_qkv^T (Q-scaled) + W_out^T in f16 -------
__global__ __launch_bounds__(256) void prep(
    const float* __restrict__ Wqkv,
    const float* __restrict__ Wout,
    _Float16* __restrict__ WqkvT,   // [384][128], rows 0..127 pre-scaled by QSCALE
    _Float16* __restrict__ WoutT)   // [128][128]
{
    const int id = blockIdx.x*256 + threadIdx.x;
    if (id < 384*128) {
        const int n = id >> 7, k = id & 127;
        const float s = (n < 128) ? QSCALE : 1.0f;
        WqkvT[id] = (_Float16)(Wqkv[k*384 + n] * s);
    } else if (id < 384*128 + 128*128) {
        const int e = id - 384*128;
        const int n = e >> 7, k = e & 127;
        WoutT[e] = (_Float16)(Wout[k*128 + n]);
    }
}

// ---------------- K1: qkv = x @ WqkvT^T + b, via K=32 MFMA (R18-frozen) -------
__global__ __launch_bounds__(256) void qkv_mfma(
    const float* __restrict__ x,
    const _Float16* __restrict__ WqkvT,
    const float* __restrict__ bqkv,
    _Float16* __restrict__ Qh,    // [BH][NNP][16]
    _Float16* __restrict__ Kh,    // [BH][NNP][16]
    _Float16* __restrict__ Vt)    // [BH][16][NNP] (transposed, attn-ready)
{
    __shared__ _Float16 tile[16][264];            // [local token][ntc*16+dim] Q/K only
    const int wid  = blockIdx.x;                  // m-tile 0..1024
    const int wave = threadIdx.x >> 6;            // 0..3 -> nt chunk
    const int lane = threadIdx.x & 63;
    const int quad = lane >> 4, l16 = lane & 15;

    const int rowlo = wid*16;
    const int blo   = rowlo / NN;
    const bool vfast = (rowlo + 15 < ROWS) && (rowlo + 15 - blo*NN < NN);
    const int nrow0 = rowlo - blo*NN;

    const int arow = rowlo + l16;
    const int arc  = (arow < ROWS) ? arow : (ROWS - 1);
    const float* xr = x + (size_t)arc*DD;
    h8 af[4];
    #pragma unroll
    for (int kk = 0; kk < 4; ++kk) {
        const float4 t0 = *(const float4*)(xr + kk*32 + quad*8);
        const float4 t1 = *(const float4*)(xr + kk*32 + quad*8 + 4);
        af[kk] = pack8u(t0, t1);
    }

    const int nt0 = wave*6;

    for (int nt = nt0; nt < nt0 + 6; nt += 2) {
        const float b0 = bqkv[nt*16 + l16]      * ((nt   < 8) ? QSCALE : 1.0f);
        const float b1 = bqkv[nt*16 + 16 + l16] * ((nt+1 < 8) ? QSCALE : 1.0f);
        f4 a0 = {b0,b0,b0,b0}, a1 = {b1,b1,b1,b1};
        #pragma unroll
        for (int kk = 0; kk < 4; ++kk) {
            const h8 bf0 = *(const h8*)(WqkvT + (size_t)(nt*16      + l16)*DD + kk*32 + quad*8);
            const h8 bf1 = *(const h8*)(WqkvT + (size_t)(nt*16 + 16 + l16)*DD + kk*32 + quad*8);
            a0 = __builtin_amdgcn_mfma_f32_16x16x32_f16(af[kk], bf0, a0, 0, 0, 0);
            a1 = __builtin_amdgcn_mfma_f32_16x16x32_f16(af[kk], bf1, a1, 0, 0, 0);
        }
        #pragma unroll
        for (int u = 0; u < 2; ++u) {
            const int ntc = nt + u;
            const f4 av = u ? a1 : a0;
            if (ntc < 16) {        // Q/K -> LDS stage
                #pragma unroll
                for (int r = 0; r < 4; ++r)
                    tile[quad*4 + r][ntc*16 + l16] = (_Float16)av[r];
            } else {               // V -> direct transposed store
                const int head = ntc & 7;
                if (vfast) {
                    h4 pk;
                    pk[0] = (_Float16)av[0]; pk[1] = (_Float16)av[1];
                    pk[2] = (_Float16)av[2]; pk[3] = (_Float16)av[3];
                    *(h4*)(Vt + ((size_t)(blo*HH + head)*DH + l16)*NNP + nrow0 + quad*4) = pk;
                } else {
                    #pragma unroll
                    for (int r = 0; r < 4; ++r) {
                        const int row = rowlo + quad*4 + r;
                        if (row < ROWS) {
                            const int bidx = row / NN;
                            const int nrow = row - bidx*NN;
                            Vt[((size_t)(bidx*HH + head)*DH + l16)*NNP + nrow] = (_Float16)av[r];
                        }
                    }
                }
            }
        }
    }
    __syncthreads();

    // write phase (Q/K): unit = (ntc, local token); 16-dim head-row = 2x h8 (32B)
    {
        const int u   = threadIdx.x;   // 0..255 == 16 ntc x 16 tokens
        const int ntc = u >> 4, lt = u & 15;
        const int row = rowlo + lt;
        if (row < ROWS) {
            _Float16* base = (ntc < 8) ? Qh : Kh;
            const int head = ntc & 7;
            const int bidx = row / NN;
            const int nrow = row - bidx*NN;
            _Float16* dst = base + ((size_t)(bidx*HH + head)*NNP + nrow)*DH;
            *(h8*)dst       = *(const h8*)&tile[lt][ntc*16];
            *(h8*)(dst + 8) = *(const h8*)&tile[lt][ntc*16 + 8];
        }
    }
}

// ---------------- K2: MFMA flash attention (R13/R18 body; R25 PACC layout) ----
// R27: launched as two qt-halves (qt_off scalar arg) so qkv/out can surface
// in the top-5 dispatch table. Body otherwise byte-identical to R25.
__global__ __launch_bounds__(256, 8) void attn_mfma(
    const _Float16* __restrict__ Qh,
    const _Float16* __restrict__ Kh,
    const _Float16* __restrict__ Vt,
    _Float16* __restrict__ PACC,   // [ROWS][NSP][DD] per-split normalized out (f16)
    float* __restrict__ PL,        // [ROWS][HH][NSP] per-split row sums
    int qt_off)
{
    const int qt   = blockIdx.x + qt_off;   // 0..16
    const int bh   = blockIdx.y;       // 0..31
    const int sp   = blockIdx.z;       // 0..3
    const int tid  = threadIdx.x;
    const int wave = tid >> 6;
    const int lane = tid & 63;
    const int quad = lane >> 4;
    const int l16  = lane & 15;
    const int bidx = bh >> 3, head = bh & 7;

    const int qbase = qt*256 + wave*64;

    const _Float16* Qb = Qh + (size_t)bh*NNP*DH;
    h4 qf[4];
    #pragma unroll
    for (int g = 0; g < 4; ++g) {
        const int qr = qbase + g*16 + l16;
        const int qc = (qr < NN) ? qr : (NN-1);
        qf[g] = *(const h4*)(Qb + (size_t)qc*DH + quad*4);
    }

    f4 acc[4] = {{0,0,0,0},{0,0,0,0},{0,0,0,0},{0,0,0,0}};
    float ls[4] = {0.f,0.f,0.f,0.f};

    const int t0 = sp*64;
    const int t1 = t0 + 64;

    const _Float16* kp = Kh + ((size_t)bh*NNP + (size_t)t0*16 + l16)*DH + quad*4;
    const _Float16* vp = Vt + ((size_t)bh*DH + l16)*NNP + t0*16 + quad*4;

    h4 ak = *(const h4*)kp;
    h4 av = *(const h4*)vp;
    const f4 zero = {0.f,0.f,0.f,0.f};
#if __has_builtin(__builtin_amdgcn_fdot2)
    const fp16v2 one2 = {(__fp16)1.0f, (__fp16)1.0f};
#endif

    for (int tt = t0; tt < t1; ++tt) {
        kp += 16*DH; vp += 16;
        const h4 nak = *(const h4*)kp;   // prefetch (tile <= 256 in-bounds)
        const h4 nav = *(const h4*)vp;
        #pragma unroll
        for (int g = 0; g < 4; ++g) {
            f4 d = __builtin_amdgcn_mfma_f32_16x16x16f16(ak, qf[g], zero, 0, 0, 0);
            const float p0 = EXP2F(d[0]), p1 = EXP2F(d[1]), p2 = EXP2F(d[2]), p3 = EXP2F(d[3]);
            const H4u pb = pack4u(p0, p1, p2, p3);
#if __has_builtin(__builtin_amdgcn_fdot2)
            ls[g] = __builtin_amdgcn_fdot2(pb.p[0], one2,
                     __builtin_amdgcn_fdot2(pb.p[1], one2, ls[g], false), false);
#else
            ls[g] += (p0 + p1) + (p2 + p3);
#endif
            acc[g] = __builtin_amdgcn_mfma_f32_16x16x16f16(av, pb.v, acc[g], 0, 0, 0);
        }
        ak = nak; av = nav;
    }

    if (sp == 3) {   // tile 256: keys 4096..4111; only key 4096 (quad==0, reg 0) valid
        #pragma unroll
        for (int g = 0; g < 4; ++g) {
            f4 d = __builtin_amdgcn_mfma_f32_16x16x16f16(ak, qf[g], zero, 0, 0, 0);
            const float p0 = (quad == 0) ? EXP2F(d[0]) : 0.f;
            ls[g] += p0;
            const H4u pb = pack4u(p0, 0.f, 0.f, 0.f);
            acc[g] = __builtin_amdgcn_mfma_f32_16x16x16f16(av, pb.v, acc[g], 0, 0, 0);
        }
    }

    #pragma unroll
    for (int g = 0; g < 4; ++g) {
        float l = ls[g];
        l += __shfl_xor(l, 16);
        l += __shfl_xor(l, 32);
        const int qr = qbase + g*16 + l16;
        if (qr < NN) {
            const size_t row = (size_t)bidx*NN + qr;
            const float inv = 1.0f / l;   // per-split normalize: f16-safe range
            const H4u st = pack4u(acc[g][0]*inv, acc[g][1]*inv, acc[g][2]*inv, acc[g][3]*inv);
            *(h4*)(PACC + (row*NSP + sp)*DD + head*DH + quad*4) = st.v;
            if (quad == 0) PL[(row*HH + head)*NSP + sp] = l;
        }
    }
}

// ---------------- K3: merged-AO @ Wout + b via K=32 MFMA (R25 dense merge) ----
__global__ __launch_bounds__(256) void out_mfma(
    const _Float16* __restrict__ PACC,    // [ROWS][NSP][DD]
    const float* __restrict__ PL,         // [ROWS][HH][NSP]
    const _Float16* __restrict__ WoutT,   // [128][128]
    const float* __restrict__ bout,
    float* __restrict__ out)
{
    __shared__ _Float16 afl[16][136];     // [token][dim], +8 pad
    const int wid  = blockIdx.x;          // m-tile 0..1024
    const int tid  = threadIdx.x;
    const int wave = tid >> 6;
    const int lane = tid & 63;
    const int quad = lane >> 4, l16 = lane & 15;
    const int nt   = wave*2;

    // hoist Wout + bias early (independent of merge phase)
    h8 wf[2][4];
    #pragma unroll
    for (int u = 0; u < 2; ++u)
        #pragma unroll
        for (int kk = 0; kk < 4; ++kk)
            wf[u][kk] = *(const h8*)(WoutT + (size_t)((nt+u)*16 + l16)*DD + kk*32 + quad*8);
    const float b0 = bout[nt*16 + l16];
    const float b1 = bout[nt*16 + 16 + l16];

    // ---- phase 1: merge splits for 16 tokens x 128 dims into LDS
    // PACC row block = [NSP][DD] = 1KB dense; PL row entry = float4.
    {
        const int t   = tid >> 4;         // local token 0..15
        const int seg = tid & 15;         // dim octet 0..15 (dims seg*8..+8)
        const int head = seg >> 1;
        const int arow = wid*16 + t;
        const int arc  = (arow < ROWS) ? arow : (ROWS - 1);
        const f4 lv = *(const f4*)(PL + ((size_t)arc*HH + head)*NSP);
        const float lsum = (lv[0] + lv[1]) + (lv[2] + lv[3]);
        const float inv = 1.0f / lsum;
        const _Float16* pb = PACC + (size_t)arc*NSP*DD + seg*8;
        float m[8] = {0,0,0,0,0,0,0,0};
        #pragma unroll
        for (int sp = 0; sp < NSP; ++sp) {
            const float s = lv[sp]*inv;
            const h8 p = *(const h8*)(pb + sp*DD);
            #pragma unroll
            for (int j = 0; j < 8; ++j) m[j] += s*(float)p[j];
        }
        H8u u;
#if __has_builtin(__builtin_amdgcn_cvt_pkrtz)
        u.p[0] = __builtin_amdgcn_cvt_pkrtz(m[0], m[1]);
        u.p[1] = __builtin_amdgcn_cvt_pkrtz(m[2], m[3]);
        u.p[2] = __builtin_amdgcn_cvt_pkrtz(m[4], m[5]);
        u.p[3] = __builtin_amdgcn_cvt_pkrtz(m[6], m[7]);
#else
        #pragma unroll
        for (int j = 0; j < 8; ++j) u.v[j] = (_Float16)m[j];
#endif
        *(h8*)&afl[t][seg*8] = u.v;
    }
    __syncthreads();

    // ---- phase 2: GEMM vs WoutT; wave handles n-tiles nt, nt+1
    h8 af[4];
    #pragma unroll
    for (int kk = 0; kk < 4; ++kk)
        af[kk] = *(const h8*)&afl[l16][kk*32 + quad*8];

    f4 a0 = {b0,b0,b0,b0}, a1 = {b1,b1,b1,b1};
    #pragma unroll
    for (int kk = 0; kk < 4; ++kk) {
        a0 = __builtin_amdgcn_mfma_f32_16x16x32_f16(af[kk], wf[0][kk], a0, 0, 0, 0);
        a1 = __builtin_amdgcn_mfma_f32_16x16x32_f16(af[kk], wf[1][kk], a1, 0, 0, 0);
    }
    const int r0 = wid*16 + quad*4;
    #pragma unroll
    for (int r = 0; r < 4; ++r) {
        const int row = r0 + r;
        if (row < ROWS) {
            out[(size_t)row*DD + nt*16      + l16] = a0[r];
            out[(size_t)row*DD + nt*16 + 16 + l16] = a1[r];
        }
    }
}

extern "C" void kernel_launch(void* const* d_in, const int* in_sizes, int n_in,
                              void* d_out, int out_size, void* d_ws, size_t ws_size,
                              hipStream_t stream) {
    const float* x    = (const float*)d_in[0];
    const float* Wqkv = (const float*)d_in[1];
    const float* bqkv = (const float*)d_in[2];
    const float* Wout = (const float*)d_in[3];
    const float* bout = (const float*)d_in[4];
    for (int i = 0; i < n_in; ++i) {
        switch (in_sizes[i]) {
            case 2097664: x    = (const float*)d_in[i]; break;
            case 49152:   Wqkv = (const float*)d_in[i]; break;
            case 384:     bqkv = (const float*)d_in[i]; break;
            case 16384:   Wout = (const float*)d_in[i]; break;
            case 128:     bout = (const float*)d_in[i]; break;
            default: break;
        }
    }
    float* out = (float*)d_out;

    const size_t perh = (size_t)BH * NNP * DH;            // 2,105,344 f16
    _Float16* Qh   = (_Float16*)d_ws;                     // 4.21 MB
    _Float16* Kh   = Qh + perh;                           // 4.21 MB
    _Float16* Vt   = Kh + perh;                           // 4.21 MB
    _Float16* PACC = Vt + perh;                           // [ROWS][NSP][DD] f16 16.78 MB
    float*    PL    = (float*)(PACC + (size_t)NSP*ROWS*DD); // [ROWS][HH][NSP] 2.1 MB
    _Float16* WqkvT = (_Float16*)(PL + (size_t)NSP*ROWS*HH);// 96 KB
    _Float16* WoutT = WqkvT + 384*128;                    // 32 KB -> total ~31.6 MB

    const int prep_total = 384*128 + 128*128;

    hipLaunchKernelGGL(prep, dim3((prep_total + 255)/256), dim3(256), 0, stream,
                       Wqkv, Wout, WqkvT, WoutT);
    hipLaunchKernelGGL(qkv_mfma, dim3(MT), dim3(256), 0, stream,
                       x, WqkvT, bqkv, Qh, Kh, Vt);
    // R27 diagnostic: attn as two qt-halves so other kernels can surface.
    hipLaunchKernelGGL(attn_mfma, dim3(9, BH, NSP), dim3(256), 0, stream,
                       Qh, Kh, Vt, PACC, PL, 0);
    hipLaunchKernelGGL(attn_mfma, dim3(8, BH, NSP), dim3(256), 0, stream,
                       Qh, Kh, Vt, PACC, PL, 9);
    hipLaunchKernelGGL(out_mfma, dim3(MT), dim3(256), 0, stream,
                       PACC, PL, WoutT, bout, out);
}

// Round 15
// 175.800 us; speedup vs baseline: 1.0443x; 1.0443x over previous
//
#include <hip/hip_runtime.h>
#include <hip/hip_bf16.h>
#include <stdint.h>

// Attention: b=4, n=4097, d=128, h=8, dh=16, scale = d**-0.5.
// Interface (R5): fp32 in, fp32 out, ws >= 33.6MB usable.
// R28: FINAL — revert to R25 verbatim (best measured: 175.9us).
// Evidence ledger: attn = 88.4us, issue-port-saturated (VALU 66% + MFMA 35%
// ~= 101%; 76% of the 67us instruction floor: 27us exp2 is one
// transcendental per score, algorithm-required). 8 attn edits regressed.
// Non-attn residual proven implementation-INVARIANT: out (R21 lightest
// possible: no change), qkv waves (R26), layouts (R25 +-2us); R27's split
// diagnostic shows the residual shrinks as attn is split (87->74->56us for
// 1/2/4 dispatches with identical other kernels) => it is launch/drain/
// fixed-graph overhead, not kernel time. This decomposition is at its
// practical floor.

#define BB 4
#define NN 4097
#define NNP 4112
#define DD 128
#define HH 8
#define DH 16
#define BH (BB*HH)    // 32
#define ROWS (BB*NN)  // 16388
#define MT  1025      // ceil(ROWS/16) m-tiles
#define NSP 4         // attention key-splits (R13-proven)

typedef _Float16 h4 __attribute__((ext_vector_type(4)));
typedef _Float16 h8 __attribute__((ext_vector_type(8)));
typedef __fp16   fp16v2 __attribute__((ext_vector_type(2)));
typedef float    f4 __attribute__((ext_vector_type(4)));

#define QSCALE (0.08838834764831845f * 1.4426950408889634f)  // 128^-.5 * log2e

#if __has_builtin(__builtin_amdgcn_exp2f)
#define EXP2F(x) __builtin_amdgcn_exp2f(x)
#else
#define EXP2F(x) exp2f(x)
#endif

union H4u { h4 v; fp16v2 p[2]; };
union H8u { h8 v; fp16v2 p[4]; };

static __device__ __forceinline__ H4u pack4u(float a, float b, float c, float d) {
    H4u u;
#if __has_builtin(__builtin_amdgcn_cvt_pkrtz)
    u.p[0] = __builtin_amdgcn_cvt_pkrtz(a, b);
    u.p[1] = __builtin_amdgcn_cvt_pkrtz(c, d);
#else
    u.v[0] = (_Float16)a; u.v[1] = (_Float16)b; u.v[2] = (_Float16)c; u.v[3] = (_Float16)d;
#endif
    return u;
}

static __device__ __forceinline__ h8 pack8u(const float4& t0, const float4& t1) {
    H8u u;
#if __has_builtin(__builtin_amdgcn_cvt_pkrtz)
    u.p[0] = __builtin_amdgcn_cvt_pkrtz(t0.x, t0.y);
    u.p[1] = __builtin_amdgcn_cvt_pkrtz(t0.z, t0.w);
    u.p[2] = __builtin_amdgcn_cvt_pkrtz(t1.x, t1.y);
    u.p[3] = __builtin_amdgcn_cvt_pkrtz(t1.z, t1.w);
#else
    u.v[0]=(_Float16)t0.x; u.v[1]=(_Float16)t0.y; u.v[2]=(_Float16)t0.z; u.v[3]=(_Float16)t0.w;
    u.v[4]=(_Float16)t1.x; u.v[5]=(_Float16)t1.y; u.v[6]=(_Float16)t1.z; u.v[7]=(_Float16)t1.w;
#endif
    return u.v;
}

// ---------------- K0: prep — W_qkv^T (Q-scaled) + W_out^T in f16 -------
__global__ __launch_bounds__(256) void prep(
    const float* __restrict__ Wqkv,
    const float* __restrict__ Wout,
    _Float16* __restrict__ WqkvT,   // [384][128], rows 0..127 pre-scaled by QSCALE
    _Float16* __restrict__ WoutT)   // [128][128]
{
    const int id = blockIdx.x*256 + threadIdx.x;
    if (id < 384*128) {
        const int n = id >> 7, k = id & 127;
        const float s = (n < 128) ? QSCALE : 1.0f;
        WqkvT[id] = (_Float16)(Wqkv[k*384 + n] * s);
    } else if (id < 384*128 + 128*128) {
        const int e = id - 384*128;
        const int n = e >> 7, k = e & 127;
        WoutT[e] = (_Float16)(Wout[k*128 + n]);
    }
}

// ---------------- K1: qkv = x @ WqkvT^T + b, via K=32 MFMA (R18-frozen) -------
__global__ __launch_bounds__(256) void qkv_mfma(
    const float* __restrict__ x,
    const _Float16* __restrict__ WqkvT,
    const float* __restrict__ bqkv,
    _Float16* __restrict__ Qh,    // [BH][NNP][16]
    _Float16* __restrict__ Kh,    // [BH][NNP][16]
    _Float16* __restrict__ Vt)    // [BH][16][NNP] (transposed, attn-ready)
{
    __shared__ _Float16 tile[16][264];            // [local token][ntc*16+dim] Q/K only
    const int wid  = blockIdx.x;                  // m-tile 0..1024
    const int wave = threadIdx.x >> 6;            // 0..3 -> nt chunk
    const int lane = threadIdx.x & 63;
    const int quad = lane >> 4, l16 = lane & 15;

    const int rowlo = wid*16;
    const int blo   = rowlo / NN;
    const bool vfast = (rowlo + 15 < ROWS) && (rowlo + 15 - blo*NN < NN);
    const int nrow0 = rowlo - blo*NN;

    const int arow = rowlo + l16;
    const int arc  = (arow < ROWS) ? arow : (ROWS - 1);
    const float* xr = x + (size_t)arc*DD;
    h8 af[4];
    #pragma unroll
    for (int kk = 0; kk < 4; ++kk) {
        const float4 t0 = *(const float4*)(xr + kk*32 + quad*8);
        const float4 t1 = *(const float4*)(xr + kk*32 + quad*8 + 4);
        af[kk] = pack8u(t0, t1);
    }

    const int nt0 = wave*6;

    for (int nt = nt0; nt < nt0 + 6; nt += 2) {
        const float b0 = bqkv[nt*16 + l16]      * ((nt   < 8) ? QSCALE : 1.0f);
        const float b1 = bqkv[nt*16 + 16 + l16] * ((nt+1 < 8) ? QSCALE : 1.0f);
        f4 a0 = {b0,b0,b0,b0}, a1 = {b1,b1,b1,b1};
        #pragma unroll
        for (int kk = 0; kk < 4; ++kk) {
            const h8 bf0 = *(const h8*)(WqkvT + (size_t)(nt*16      + l16)*DD + kk*32 + quad*8);
            const h8 bf1 = *(const h8*)(WqkvT + (size_t)(nt*16 + 16 + l16)*DD + kk*32 + quad*8);
            a0 = __builtin_amdgcn_mfma_f32_16x16x32_f16(af[kk], bf0, a0, 0, 0, 0);
            a1 = __builtin_amdgcn_mfma_f32_16x16x32_f16(af[kk], bf1, a1, 0, 0, 0);
        }
        #pragma unroll
        for (int u = 0; u < 2; ++u) {
            const int ntc = nt + u;
            const f4 av = u ? a1 : a0;
            if (ntc < 16) {        // Q/K -> LDS stage
                #pragma unroll
                for (int r = 0; r < 4; ++r)
                    tile[quad*4 + r][ntc*16 + l16] = (_Float16)av[r];
            } else {               // V -> direct transposed store
                const int head = ntc & 7;
                if (vfast) {
                    h4 pk;
                    pk[0] = (_Float16)av[0]; pk[1] = (_Float16)av[1];
                    pk[2] = (_Float16)av[2]; pk[3] = (_Float16)av[3];
                    *(h4*)(Vt + ((size_t)(blo*HH + head)*DH + l16)*NNP + nrow0 + quad*4) = pk;
                } else {
                    #pragma unroll
                    for (int r = 0; r < 4; ++r) {
                        const int row = rowlo + quad*4 + r;
                        if (row < ROWS) {
                            const int bidx = row / NN;
                            const int nrow = row - bidx*NN;
                            Vt[((size_t)(bidx*HH + head)*DH + l16)*NNP + nrow] = (_Float16)av[r];
                        }
                    }
                }
            }
        }
    }
    __syncthreads();

    // write phase (Q/K): unit = (ntc, local token); 16-dim head-row = 2x h8 (32B)
    {
        const int u   = threadIdx.x;   // 0..255 == 16 ntc x 16 tokens
        const int ntc = u >> 4, lt = u & 15;
        const int row = rowlo + lt;
        if (row < ROWS) {
            _Float16* base = (ntc < 8) ? Qh : Kh;
            const int head = ntc & 7;
            const int bidx = row / NN;
            const int nrow = row - bidx*NN;
            _Float16* dst = base + ((size_t)(bidx*HH + head)*NNP + nrow)*DH;
            *(h8*)dst       = *(const h8*)&tile[lt][ntc*16];
            *(h8*)(dst + 8) = *(const h8*)&tile[lt][ntc*16 + 8];
        }
    }
}

// ---------------- K2: MFMA flash attention (R13/R18 body; R25 PACC layout) ----
__global__ __launch_bounds__(256, 8) void attn_mfma(
    const _Float16* __restrict__ Qh,
    const _Float16* __restrict__ Kh,
    const _Float16* __restrict__ Vt,
    _Float16* __restrict__ PACC,   // [ROWS][NSP][DD] per-split normalized out (f16)
    float* __restrict__ PL)        // [ROWS][HH][NSP] per-split row sums
{
    const int qt   = blockIdx.x;       // 0..16
    const int bh   = blockIdx.y;       // 0..31
    const int sp   = blockIdx.z;       // 0..3
    const int tid  = threadIdx.x;
    const int wave = tid >> 6;
    const int lane = tid & 63;
    const int quad = lane >> 4;
    const int l16  = lane & 15;
    const int bidx = bh >> 3, head = bh & 7;

    const int qbase = qt*256 + wave*64;

    const _Float16* Qb = Qh + (size_t)bh*NNP*DH;
    h4 qf[4];
    #pragma unroll
    for (int g = 0; g < 4; ++g) {
        const int qr = qbase + g*16 + l16;
        const int qc = (qr < NN) ? qr : (NN-1);
        qf[g] = *(const h4*)(Qb + (size_t)qc*DH + quad*4);
    }

    f4 acc[4] = {{0,0,0,0},{0,0,0,0},{0,0,0,0},{0,0,0,0}};
    float ls[4] = {0.f,0.f,0.f,0.f};

    const int t0 = sp*64;
    const int t1 = t0 + 64;

    const _Float16* kp = Kh + ((size_t)bh*NNP + (size_t)t0*16 + l16)*DH + quad*4;
    const _Float16* vp = Vt + ((size_t)bh*DH + l16)*NNP + t0*16 + quad*4;

    h4 ak = *(const h4*)kp;
    h4 av = *(const h4*)vp;
    const f4 zero = {0.f,0.f,0.f,0.f};
#if __has_builtin(__builtin_amdgcn_fdot2)
    const fp16v2 one2 = {(__fp16)1.0f, (__fp16)1.0f};
#endif

    for (int tt = t0; tt < t1; ++tt) {
        kp += 16*DH; vp += 16;
        const h4 nak = *(const h4*)kp;   // prefetch (tile <= 256 in-bounds)
        const h4 nav = *(const h4*)vp;
        #pragma unroll
        for (int g = 0; g < 4; ++g) {
            f4 d = __builtin_amdgcn_mfma_f32_16x16x16f16(ak, qf[g], zero, 0, 0, 0);
            const float p0 = EXP2F(d[0]), p1 = EXP2F(d[1]), p2 = EXP2F(d[2]), p3 = EXP2F(d[3]);
            const H4u pb = pack4u(p0, p1, p2, p3);
#if __has_builtin(__builtin_amdgcn_fdot2)
            ls[g] = __builtin_amdgcn_fdot2(pb.p[0], one2,
                     __builtin_amdgcn_fdot2(pb.p[1], one2, ls[g], false), false);
#else
            ls[g] += (p0 + p1) + (p2 + p3);
#endif
            acc[g] = __builtin_amdgcn_mfma_f32_16x16x16f16(av, pb.v, acc[g], 0, 0, 0);
        }
        ak = nak; av = nav;
    }

    if (sp == 3) {   // tile 256: keys 4096..4111; only key 4096 (quad==0, reg 0) valid
        #pragma unroll
        for (int g = 0; g < 4; ++g) {
            f4 d = __builtin_amdgcn_mfma_f32_16x16x16f16(ak, qf[g], zero, 0, 0, 0);
            const float p0 = (quad == 0) ? EXP2F(d[0]) : 0.f;
            ls[g] += p0;
            const H4u pb = pack4u(p0, 0.f, 0.f, 0.f);
            acc[g] = __builtin_amdgcn_mfma_f32_16x16x16f16(av, pb.v, acc[g], 0, 0, 0);
        }
    }

    #pragma unroll
    for (int g = 0; g < 4; ++g) {
        float l = ls[g];
        l += __shfl_xor(l, 16);
        l += __shfl_xor(l, 32);
        const int qr = qbase + g*16 + l16;
        if (qr < NN) {
            const size_t row = (size_t)bidx*NN + qr;
            const float inv = 1.0f / l;   // per-split normalize: f16-safe range
            const H4u st = pack4u(acc[g][0]*inv, acc[g][1]*inv, acc[g][2]*inv, acc[g][3]*inv);
            *(h4*)(PACC + (row*NSP + sp)*DD + head*DH + quad*4) = st.v;
            if (quad == 0) PL[(row*HH + head)*NSP + sp] = l;
        }
    }
}

// ---------------- K3: merged-AO @ Wout + b via K=32 MFMA (R25 dense merge) ----
__global__ __launch_bounds__(256) void out_mfma(
    const _Float16* __restrict__ PACC,    // [ROWS][NSP][DD]
    const float* __restrict__ PL,         // [ROWS][HH][NSP]
    const _Float16* __restrict__ WoutT,   // [128][128]
    const float* __restrict__ bout,
    float* __restrict__ out)
{
    __shared__ _Float16 afl[16][136];     // [token][dim], +8 pad
    const int wid  = blockIdx.x;          // m-tile 0..1024
    const int tid  = threadIdx.x;
    const int wave = tid >> 6;
    const int lane = tid & 63;
    const int quad = lane >> 4, l16 = lane & 15;
    const int nt   = wave*2;

    // hoist Wout + bias early (independent of merge phase)
    h8 wf[2][4];
    #pragma unroll
    for (int u = 0; u < 2; ++u)
        #pragma unroll
        for (int kk = 0; kk < 4; ++kk)
            wf[u][kk] = *(const h8*)(WoutT + (size_t)((nt+u)*16 + l16)*DD + kk*32 + quad*8);
    const float b0 = bout[nt*16 + l16];
    const float b1 = bout[nt*16 + 16 + l16];

    // ---- phase 1: merge splits for 16 tokens x 128 dims into LDS
    // PACC row block = [NSP][DD] = 1KB dense; PL row entry = float4.
    {
        const int t   = tid >> 4;         // local token 0..15
        const int seg = tid & 15;         // dim octet 0..15 (dims seg*8..+8)
        const int head = seg >> 1;
        const int arow = wid*16 + t;
        const int arc  = (arow < ROWS) ? arow : (ROWS - 1);
        const f4 lv = *(const f4*)(PL + ((size_t)arc*HH + head)*NSP);
        const float lsum = (lv[0] + lv[1]) + (lv[2] + lv[3]);
        const float inv = 1.0f / lsum;
        const _Float16* pb = PACC + (size_t)arc*NSP*DD + seg*8;
        float m[8] = {0,0,0,0,0,0,0,0};
        #pragma unroll
        for (int sp = 0; sp < NSP; ++sp) {
            const float s = lv[sp]*inv;
            const h8 p = *(const h8*)(pb + sp*DD);
            #pragma unroll
            for (int j = 0; j < 8; ++j) m[j] += s*(float)p[j];
        }
        H8u u;
#if __has_builtin(__builtin_amdgcn_cvt_pkrtz)
        u.p[0] = __builtin_amdgcn_cvt_pkrtz(m[0], m[1]);
        u.p[1] = __builtin_amdgcn_cvt_pkrtz(m[2], m[3]);
        u.p[2] = __builtin_amdgcn_cvt_pkrtz(m[4], m[5]);
        u.p[3] = __builtin_amdgcn_cvt_pkrtz(m[6], m[7]);
#else
        #pragma unroll
        for (int j = 0; j < 8; ++j) u.v[j] = (_Float16)m[j];
#endif
        *(h8*)&afl[t][seg*8] = u.v;
    }
    __syncthreads();

    // ---- phase 2: GEMM vs WoutT; wave handles n-tiles nt, nt+1
    h8 af[4];
    #pragma unroll
    for (int kk = 0; kk < 4; ++kk)
        af[kk] = *(const h8*)&afl[l16][kk*32 + quad*8];

    f4 a0 = {b0,b0,b0,b0}, a1 = {b1,b1,b1,b1};
    #pragma unroll
    for (int kk = 0; kk < 4; ++kk) {
        a0 = __builtin_amdgcn_mfma_f32_16x16x32_f16(af[kk], wf[0][kk], a0, 0, 0, 0);
        a1 = __builtin_amdgcn_mfma_f32_16x16x32_f16(af[kk], wf[1][kk], a1, 0, 0, 0);
    }
    const int r0 = wid*16 + quad*4;
    #pragma unroll
    for (int r = 0; r < 4; ++r) {
        const int row = r0 + r;
        if (row < ROWS) {
            out[(size_t)row*DD + nt*16      + l16] = a0[r];
            out[(size_t)row*DD + nt*16 + 16 + l16] = a1[r];
        }
    }
}

extern "C" void kernel_launch(void* const* d_in, const int* in_sizes, int n_in,
                              void* d_out, int out_size, void* d_ws, size_t ws_size,
                              hipStream_t stream) {
    const float* x    = (const float*)d_in[0];
    const float* Wqkv = (const float*)d_in[1];
    const float* bqkv = (const float*)d_in[2];
    const float* Wout = (const float*)d_in[3];
    const float* bout = (const float*)d_in[4];
    for (int i = 0; i < n_in; ++i) {
        switch (in_sizes[i]) {
            case 2097664: x    = (const float*)d_in[i]; break;
            case 49152:   Wqkv = (const float*)d_in[i]; break;
            case 384:     bqkv = (const float*)d_in[i]; break;
            case 16384:   Wout = (const float*)d_in[i]; break;
            case 128:     bout = (const float*)d_in[i]; break;
            default: break;
        }
    }
    float* out = (float*)d_out;

    const size_t perh = (size_t)BH * NNP * DH;            // 2,105,344 f16
    _Float16* Qh   = (_Float16*)d_ws;                     // 4.21 MB
    _Float16* Kh   = Qh + perh;                           // 4.21 MB
    _Float16* Vt   = Kh + perh;                           // 4.21 MB
    _Float16* PACC = Vt + perh;                           // [ROWS][NSP][DD] f16 16.78 MB
    float*    PL    = (float*)(PACC + (size_t)NSP*ROWS*DD); // [ROWS][HH][NSP] 2.1 MB
    _Float16* WqkvT = (_Float16*)(PL + (size_t)NSP*ROWS*HH);// 96 KB
    _Float16* WoutT = WqkvT + 384*128;                    // 32 KB -> total ~31.6 MB

    const int prep_total = 384*128 + 128*128;

    hipLaunchKernelGGL(prep, dim3((prep_total + 255)/256), dim3(256), 0, stream,
                       Wqkv, Wout, WqkvT, WoutT);
    hipLaunchKernelGGL(qkv_mfma, dim3(MT), dim3(256), 0, stream,
                       x, WqkvT, bqkv, Qh, Kh, Vt);
    hipLaunchKernelGGL(attn_mfma, dim3(17, BH, NSP), dim3(256), 0, stream,
                       Qh, Kh, Vt, PACC, PL);
    hipLaunchKernelGGL(out_mfma, dim3(MT), dim3(256), 0, stream,
                       PACC, PL, WoutT, bout, out);
}